// Round 2
// baseline (3478.812 us; speedup 1.0000x reference)
//
#include <hip/hip_runtime.h>

typedef __attribute__((ext_vector_type(8))) short short8;
typedef __attribute__((ext_vector_type(4))) float f32x4;

#define LNE 1e-5f

__device__ __forceinline__ unsigned short f2bf(float f) {
  union { float f; unsigned int u; } v; v.f = f;
  unsigned int r = v.u + 0x7fffu + ((v.u >> 16) & 1u);
  return (unsigned short)(r >> 16);
}
__device__ __forceinline__ float bf2f(unsigned short s) {
  union { unsigned int u; float f; } v; v.u = ((unsigned int)s) << 16;
  return v.f;
}
__device__ __forceinline__ unsigned int pk2(float a, float b) {
  return (unsigned int)f2bf(a) | ((unsigned int)f2bf(b) << 16);
}

// ---- weight prep: fp32 -> bf16, transposed to [n][k] ----
// ws layout (ushort elems):
//   wqkvT [1152][384]  rows: mat*384 + head*48 + e       (0 .. 442368)
//   woT   [384][384]   woT[n][d] = wo[d][n]              (442368 .. 589824)
//   w1T   [1536][384]  w1T[n][d] = w1[d][n]              (589824 .. 1179648)
//   w2T   [384][1536]  w2T[n][c] = w2[c][n]              (1179648 .. 1769472)
__global__ void prep_kernel(const float* __restrict__ wq, const float* __restrict__ wk,
                            const float* __restrict__ wv, const float* __restrict__ wo,
                            const float* __restrict__ w1, const float* __restrict__ w2,
                            unsigned short* __restrict__ ws) {
  int idx = blockIdx.x * 256 + threadIdx.x;
  if (idx < 442368) {
    int n = idx / 384, d = idx % 384;
    int mat = n / 384, rem = n % 384, head = rem / 48, e = rem % 48;
    const float* w = (mat == 0) ? wq : ((mat == 1) ? wk : wv);
    ws[idx] = f2bf(w[(head * 384 + d) * 48 + e]);
  } else if (idx < 589824) {
    int j = idx - 442368; int n = j / 384, d = j % 384;
    ws[idx] = f2bf(wo[d * 384 + n]);
  } else if (idx < 1179648) {
    int j = idx - 589824; int n = j / 384, d = j % 384;
    ws[idx] = f2bf(w1[d * 1536 + n]);
  } else if (idx < 1769472) {
    int j = idx - 1179648; int n = j / 1536, c = j % 1536;
    ws[idx] = f2bf(w2[c * 384 + n]);
  }
}

// ---- fused transformer block: one workgroup (1024 thr / 16 waves) per batch ----
// 16 waves = 4 waves/SIMD (LDS 151KB -> 1 block/CU). Attention: 2 head-sets x
// 8 waves (QKV split 8-way; S/softmax/PV on 4 waves/set). Phase 2/3 split 16
// ways; FFN double-buffers U (second buffer aliases dead qkv scratch) -> one
// barrier per chunk and FFN1 global loads overlap FFN2 compute across waves.
__global__ __launch_bounds__(1024, 4) void block_fused(
    const float* __restrict__ x,
    const float* __restrict__ bq, const float* __restrict__ bk, const float* __restrict__ bv,
    const float* __restrict__ bo, const float* __restrict__ b1, const float* __restrict__ b2,
    const float* __restrict__ g1, const float* __restrict__ be1,
    const float* __restrict__ g2, const float* __restrict__ be2,
    const unsigned short* __restrict__ wt,
    float* __restrict__ out) {
  // strides: 392 = 384+8 (row stride ≡ 4 mod 32 dwords -> 2-way bank alias only, 16B aligned)
  //          72  = 64+8  (same property)
  __shared__ __align__(16) unsigned short sH[64 * 392];   // h after LN1; h2 after LN2
  __shared__ __align__(16) unsigned short sA[64 * 392];   // attn concat; U buffer 0
  __shared__ __align__(16) unsigned short sS[25344];      // qkv sets | LN2 scratch | U buffer 1
  // sS carve (ushorts): sQ[set] at set*4608; sK[set] at 9216+set*4608; sVT[set] at 18432+set*3456

  const int tid  = threadIdx.x;
  const int wave = tid >> 6, lane = tid & 63;
  const int quad = lane >> 4, l15 = lane & 15;
  const int g = wave >> 3, w8 = wave & 7;    // head-set, wave-within-set
  const int wm4 = wave & 3, q4 = wave >> 2;  // phase-2/3 tile coords
  const int b = blockIdx.x;

  const unsigned short* wqkvT = wt;
  const unsigned short* woT   = wt + 442368;
  const unsigned short* w1T   = wt + 589824;
  const unsigned short* w2T   = wt + 1179648;

  unsigned short* sQg = sS + g * 4608;
  unsigned short* sKg = sS + 9216 + g * 4608;
  unsigned short* sVg = sS + 18432 + g * 3456;

  // ================= Phase 0: LN1, x -> sH (bf16) =================
  {
    const int r = tid >> 4, sub = tid & 15;   // 16 threads per row, 24 cols each
    const float* xr = x + ((size_t)b * 64 + r) * 384 + sub * 24;
    float s = 0.f, s2 = 0.f;
#pragma unroll
    for (int i = 0; i < 6; ++i) {
      float4 v = ((const float4*)xr)[i];
      s  += v.x + v.y + v.z + v.w;
      s2 += v.x * v.x + v.y * v.y + v.z * v.z + v.w * v.w;
    }
    s  += __shfl_xor(s, 1);  s  += __shfl_xor(s, 2);  s  += __shfl_xor(s, 4);  s  += __shfl_xor(s, 8);
    s2 += __shfl_xor(s2, 1); s2 += __shfl_xor(s2, 2); s2 += __shfl_xor(s2, 4); s2 += __shfl_xor(s2, 8);
    float mu = s * (1.f / 384.f);
    float rstd = rsqrtf(s2 * (1.f / 384.f) - mu * mu + LNE);
#pragma unroll
    for (int i = 0; i < 6; ++i) {
      float4 v = ((const float4*)xr)[i];
      int c = sub * 24 + i * 4;
      float h0 = (v.x - mu) * rstd * g1[c + 0] + be1[c + 0];
      float h1 = (v.y - mu) * rstd * g1[c + 1] + be1[c + 1];
      float h2 = (v.z - mu) * rstd * g1[c + 2] + be1[c + 2];
      float h3 = (v.w - mu) * rstd * g1[c + 3] + be1[c + 3];
      *(uint2*)&sH[r * 392 + c] = make_uint2(pk2(h0, h1), pk2(h2, h3));
    }
  }
  __syncthreads();

  // ================= Phase 1: attention, 2 heads per iteration =================
#pragma unroll 1
  for (int hp = 0; hp < 4; ++hp) {
    const int h = hp * 2 + g;
    {   // zero-pad q/k cols 48..63 of both sets (K=64 MFMA padding; P overwrote last iter)
      int set = tid >> 9, arr = (tid >> 8) & 1;
      int rr = (tid & 255) >> 2, cc = 48 + (tid & 3) * 4;
      unsigned short* base = sS + arr * 9216 + set * 4608;
      *(uint2*)&base[rr * 72 + cc] = make_uint2(0, 0);
    }
    // --- QKV projections for this set's head: 36 tiles across 8 waves ---
#pragma unroll 1
    for (int it = 0; it < 5; ++it) {
      int tile = (w8 ^ 7) + 8 * it;           // waves 4-7 take the 5th tile (0-3 do S/PV later)
      if (tile < 36) {
        int mat = tile / 12, sub = tile % 12;
        int mt = sub / 3, et = sub % 3;
        const unsigned short* bp = wqkvT + (size_t)((mat * 8 + h) * 48 + et * 16 + l15) * 384 + quad * 8;
        const unsigned short* ap = sH + (mt * 16 + l15) * 392 + quad * 8;
        f32x4 acc = {0.f, 0.f, 0.f, 0.f};
#pragma unroll
        for (int k = 0; k < 12; ++k) {
          short8 a  = *(const short8*)(ap + k * 32);
          short8 bb = *(const short8*)(bp + k * 32);
          acc = __builtin_amdgcn_mfma_f32_16x16x32_bf16(a, bb, acc, 0, 0, 0);
        }
        const float* bias = (mat == 0) ? bq : ((mat == 1) ? bk : bv);
        float bsv = bias[h * 48 + et * 16 + l15];
        if (mat == 2) {   // v -> sVT[e][s], contiguous in s -> b64 pack
          *(uint2*)&sVg[(et * 16 + l15) * 72 + mt * 16 + quad * 4] =
              make_uint2(pk2(acc[0] + bsv, acc[1] + bsv), pk2(acc[2] + bsv, acc[3] + bsv));
        } else {          // q/k -> [t][e], scalar scatter
          unsigned short* dst = (mat == 0) ? sQg : sKg;
#pragma unroll
          for (int i = 0; i < 4; ++i)
            dst[(mt * 16 + quad * 4 + i) * 72 + et * 16 + l15] = f2bf(acc[i] + bsv);
        }
      }
    }
    __syncthreads();

    if (w8 < 4) {
      // --- S = q k^T (wave owns rows 16*w8..+15), causal softmax in-register ---
      f32x4 sc[4];
#pragma unroll
      for (int ts = 0; ts < 4; ++ts) {
        f32x4 acc = {0.f, 0.f, 0.f, 0.f};
#pragma unroll
        for (int k = 0; k < 2; ++k) {
          short8 a  = *(const short8*)&sQg[(w8 * 16 + l15) * 72 + k * 32 + quad * 8];
          short8 bb = *(const short8*)&sKg[(ts * 16 + l15) * 72 + k * 32 + quad * 8];
          acc = __builtin_amdgcn_mfma_f32_16x16x32_bf16(a, bb, acc, 0, 0, 0);
        }
        sc[ts] = acc;
      }
      const float scale = 0.14433756729740645f;  // 48^-0.5
#pragma unroll
      for (int i = 0; i < 4; ++i) {
        int t = w8 * 16 + quad * 4 + i;
        float vv[4];
#pragma unroll
        for (int ts = 0; ts < 4; ++ts) {
          int s_ = ts * 16 + l15;
          float v = sc[ts][i] * scale;
          vv[ts] = (s_ <= t) ? v : -INFINITY;
        }
        float mx = fmaxf(fmaxf(vv[0], vv[1]), fmaxf(vv[2], vv[3]));
        mx = fmaxf(mx, __shfl_xor(mx, 1)); mx = fmaxf(mx, __shfl_xor(mx, 2));
        mx = fmaxf(mx, __shfl_xor(mx, 4)); mx = fmaxf(mx, __shfl_xor(mx, 8));
        float sum = 0.f;
#pragma unroll
        for (int ts = 0; ts < 4; ++ts) { vv[ts] = __expf(vv[ts] - mx); sum += vv[ts]; }
        sum += __shfl_xor(sum, 1); sum += __shfl_xor(sum, 2);
        sum += __shfl_xor(sum, 4); sum += __shfl_xor(sum, 8);
        float inv = 1.f / sum;
#pragma unroll
        for (int ts = 0; ts < 4; ++ts)         // P -> sQ[t][s] (q is dead; own rows only)
          sQg[t * 72 + ts * 16 + l15] = f2bf(vv[ts] * inv);
      }
      // --- attn^T = V^T P^T ; write attn[t][h*48+e] (b64 pack) ---
#pragma unroll
      for (int et = 0; et < 3; ++et) {
        f32x4 acc = {0.f, 0.f, 0.f, 0.f};
#pragma unroll
        for (int k = 0; k < 2; ++k) {
          short8 a  = *(const short8*)&sVg[(et * 16 + l15) * 72 + k * 32 + quad * 8];
          short8 bb = *(const short8*)&sQg[(w8 * 16 + l15) * 72 + k * 32 + quad * 8];
          acc = __builtin_amdgcn_mfma_f32_16x16x32_bf16(a, bb, acc, 0, 0, 0);
        }
        *(uint2*)&sA[(w8 * 16 + l15) * 392 + h * 48 + et * 16 + quad * 4] =
            make_uint2(pk2(acc[0], acc[1]), pk2(acc[2], acc[3]));
      }
    }
    __syncthreads();
  }

  // ================= Phase 2: out-proj + residual + LN2 =================
  {
    float* sRed = (float*)sS;                  // qkv scratch dead -> LN2 cross-wave scratch
    f32x4 oacc[6];
#pragma unroll
    for (int nl = 0; nl < 6; ++nl) oacc[nl] = (f32x4){0.f, 0.f, 0.f, 0.f};
#pragma unroll 2
    for (int k = 0; k < 12; ++k) {
      short8 a = *(const short8*)&sA[(wm4 * 16 + l15) * 392 + k * 32 + quad * 8];
#pragma unroll
      for (int nl = 0; nl < 6; ++nl) {
        int nt = q4 * 6 + nl;
        short8 bb = *(const short8*)(woT + (size_t)(nt * 16 + l15) * 384 + k * 32 + quad * 8);
        oacc[nl] = __builtin_amdgcn_mfma_f32_16x16x32_bf16(a, bb, oacc[nl], 0, 0, 0);
      }
    }
#pragma unroll
    for (int nl = 0; nl < 6; ++nl) {
      int nt = q4 * 6 + nl;
      float bov = bo[nt * 16 + l15];
#pragma unroll
      for (int i = 0; i < 4; ++i) {
        float hv = bf2f(sH[(wm4 * 16 + quad * 4 + i) * 392 + nt * 16 + l15]);
        oacc[nl][i] += bov + hv;    // r = h + attn@wo + bo
      }
    }
    // per-wave partial row stats (96 of 384 cols) -> LDS -> combine 4 quarters
    float sown[4], s2own[4];
#pragma unroll
    for (int i = 0; i < 4; ++i) {
      float s = 0.f, s2 = 0.f;
#pragma unroll
      for (int nl = 0; nl < 6; ++nl) { float v = oacc[nl][i]; s += v; s2 += v * v; }
      s  += __shfl_xor(s, 1);  s  += __shfl_xor(s, 2);  s  += __shfl_xor(s, 4);  s  += __shfl_xor(s, 8);
      s2 += __shfl_xor(s2, 1); s2 += __shfl_xor(s2, 2); s2 += __shfl_xor(s2, 4); s2 += __shfl_xor(s2, 8);
      sown[i] = s; s2own[i] = s2;
      if (l15 == 0) {
        int row = wm4 * 16 + quad * 4 + i;
        sRed[(row * 4 + q4) * 2 + 0] = s;
        sRed[(row * 4 + q4) * 2 + 1] = s2;
      }
    }
    __syncthreads();
    float mu_[4], rstd_[4];
#pragma unroll
    for (int i = 0; i < 4; ++i) {
      int row = wm4 * 16 + quad * 4 + i;
      float st = 0.f, s2t = 0.f;
#pragma unroll
      for (int q = 0; q < 4; ++q) {
        st  += sRed[(row * 4 + q) * 2 + 0];
        s2t += sRed[(row * 4 + q) * 2 + 1];
      }
      float mu = st * (1.f / 384.f);
      mu_[i] = mu;
      rstd_[i] = rsqrtf(s2t * (1.f / 384.f) - mu * mu + LNE);
    }
#pragma unroll
    for (int nl = 0; nl < 6; ++nl) {
      int n = (q4 * 6 + nl) * 16 + l15;
      float gv = g2[n], bev = be2[n];
#pragma unroll
      for (int i = 0; i < 4; ++i) {
        float h2v = (oacc[nl][i] - mu_[i]) * rstd_[i] * gv + bev;
        sH[(wm4 * 16 + quad * 4 + i) * 392 + n] = f2bf(h2v);   // h2 overwrites h (own region)
      }
    }
  }
  __syncthreads();

  // ================= Phase 3: FFN, double-buffered chunks of 384 over 1536 =================
  f32x4 facc[6];
#pragma unroll
  for (int nl = 0; nl < 6; ++nl) facc[nl] = (f32x4){0.f, 0.f, 0.f, 0.f};

  // FFN1: U^T = w1_chunk^T @ h2^T ; wave w: nt = wm4 (sH rows), mt = q4+4j (w1 cols)
  auto FFN1 = [&](int c, unsigned short* U) {
    short8 bfrag[12];
#pragma unroll
    for (int k = 0; k < 12; ++k)
      bfrag[k] = *(const short8*)&sH[(wm4 * 16 + l15) * 392 + k * 32 + quad * 8];
#pragma unroll 1
    for (int j = 0; j < 6; ++j) {
      int mt = q4 + 4 * j;
      const unsigned short* ap = w1T + (size_t)(c * 384 + mt * 16 + l15) * 384 + quad * 8;
      f32x4 acc = {0.f, 0.f, 0.f, 0.f};
#pragma unroll
      for (int k = 0; k < 12; ++k) {
        short8 a = *(const short8*)(ap + k * 32);
        acc = __builtin_amdgcn_mfma_f32_16x16x32_bf16(a, bfrag[k], acc, 0, 0, 0);
      }
      int rbase = c * 384 + mt * 16 + quad * 4;
      float u0 = fmaxf(acc[0] + b1[rbase + 0], 0.f);
      float u1 = fmaxf(acc[1] + b1[rbase + 1], 0.f);
      float u2 = fmaxf(acc[2] + b1[rbase + 2], 0.f);
      float u3 = fmaxf(acc[3] + b1[rbase + 3], 0.f);
      *(uint2*)&U[(wm4 * 16 + l15) * 392 + mt * 16 + quad * 4] =
          make_uint2(pk2(u0, u1), pk2(u2, u3));
    }
  };
  // FFN2: wave w owns rows mt=wm4, n-tiles q4*6..+5 (w2 elements read once per block)
  auto FFN2 = [&](int c, const unsigned short* U) {
#pragma unroll 2
    for (int k = 0; k < 12; ++k) {
      short8 a = *(const short8*)&U[(wm4 * 16 + l15) * 392 + k * 32 + quad * 8];
#pragma unroll
      for (int nl = 0; nl < 6; ++nl) {
        int n = (q4 * 6 + nl) * 16 + l15;
        short8 bb = *(const short8*)(w2T + (size_t)n * 1536 + c * 384 + k * 32 + quad * 8);
        facc[nl] = __builtin_amdgcn_mfma_f32_16x16x32_bf16(a, bb, facc[nl], 0, 0, 0);
      }
    }
  };

  FFN1(0, sA);
  __syncthreads();
#pragma unroll 1
  for (int c = 0; c < 4; ++c) {
    if (c < 3) FFN1(c + 1, (c & 1) ? sA : sS);  // write next chunk to the other buffer
    FFN2(c, (c & 1) ? sS : sA);                 // read current chunk
    __syncthreads();
  }

  // ================= Epilogue: out = h2 + ff + b2 =================
#pragma unroll
  for (int nl = 0; nl < 6; ++nl) {
    int n = (q4 * 6 + nl) * 16 + l15;
    float b2v = b2[n];
#pragma unroll
    for (int i = 0; i < 4; ++i) {
      int t = wm4 * 16 + quad * 4 + i;
      float v = facc[nl][i] + b2v + bf2f(sH[t * 392 + n]);
      out[((size_t)b * 64 + t) * 384 + n] = v;
    }
  }
}

extern "C" void kernel_launch(void* const* d_in, const int* in_sizes, int n_in,
                              void* d_out, int out_size, void* d_ws, size_t ws_size,
                              hipStream_t stream) {
  const float* x   = (const float*)d_in[0];
  const float* wq  = (const float*)d_in[1];
  const float* bq  = (const float*)d_in[2];
  const float* wk  = (const float*)d_in[3];
  const float* bk  = (const float*)d_in[4];
  const float* wv  = (const float*)d_in[5];
  const float* bv  = (const float*)d_in[6];
  const float* wo  = (const float*)d_in[7];
  const float* bo  = (const float*)d_in[8];
  const float* w1  = (const float*)d_in[9];
  const float* b1  = (const float*)d_in[10];
  const float* w2  = (const float*)d_in[11];
  const float* b2  = (const float*)d_in[12];
  const float* g1  = (const float*)d_in[13];
  const float* be1 = (const float*)d_in[14];
  const float* g2  = (const float*)d_in[15];
  const float* be2 = (const float*)d_in[16];
  unsigned short* wt = (unsigned short*)d_ws;
  float* out = (float*)d_out;

  int nbatch = in_sizes[0] / (64 * 384);    // 2048
  prep_kernel<<<(1769472 + 255) / 256, 256, 0, stream>>>(wq, wk, wv, wo, w1, w2, wt);
  block_fused<<<nbatch, 1024, 0, stream>>>(x, bq, bk, bv, bo, b1, b2,
                                           g1, be1, g2, be2, wt, out);
}

// Round 3
// 2089.130 us; speedup vs baseline: 1.6652x; 1.6652x over previous
//
#include <hip/hip_runtime.h>

typedef __attribute__((ext_vector_type(8))) short short8;
typedef __attribute__((ext_vector_type(4))) float f32x4;

#define LNE 1e-5f

__device__ __forceinline__ unsigned short f2bf(float f) {
  union { float f; unsigned int u; } v; v.f = f;
  unsigned int r = v.u + 0x7fffu + ((v.u >> 16) & 1u);
  return (unsigned short)(r >> 16);
}
__device__ __forceinline__ float bf2f(unsigned short s) {
  union { unsigned int u; float f; } v; v.u = ((unsigned int)s) << 16;
  return v.f;
}
__device__ __forceinline__ unsigned int pk2(float a, float b) {
  return (unsigned int)f2bf(a) | ((unsigned int)f2bf(b) << 16);
}

// ---- weight prep: fp32 -> bf16, transposed to [n][k] ----
// ws layout (ushort elems):
//   wqkvT [1152][384]  rows: mat*384 + head*48 + e       (0 .. 442368)
//   woT   [384][384]   woT[n][d] = wo[d][n]              (442368 .. 589824)
//   w1T   [1536][384]  w1T[n][d] = w1[d][n]              (589824 .. 1179648)
//   w2T   [384][1536]  w2T[n][c] = w2[c][n]              (1179648 .. 1769472)
__global__ void prep_kernel(const float* __restrict__ wq, const float* __restrict__ wk,
                            const float* __restrict__ wv, const float* __restrict__ wo,
                            const float* __restrict__ w1, const float* __restrict__ w2,
                            unsigned short* __restrict__ ws) {
  int idx = blockIdx.x * 256 + threadIdx.x;
  if (idx < 442368) {
    int n = idx / 384, d = idx % 384;
    int mat = n / 384, rem = n % 384, head = rem / 48, e = rem % 48;
    const float* w = (mat == 0) ? wq : ((mat == 1) ? wk : wv);
    ws[idx] = f2bf(w[(head * 384 + d) * 48 + e]);
  } else if (idx < 589824) {
    int j = idx - 442368; int n = j / 384, d = j % 384;
    ws[idx] = f2bf(wo[d * 384 + n]);
  } else if (idx < 1179648) {
    int j = idx - 589824; int n = j / 384, d = j % 384;
    ws[idx] = f2bf(w1[d * 1536 + n]);
  } else if (idx < 1769472) {
    int j = idx - 1179648; int n = j / 1536, c = j % 1536;
    ws[idx] = f2bf(w2[c * 384 + n]);
  }
}

// ---- fused transformer block: one workgroup (512 thr / 8 waves) per batch ----
// 8 waves = 2 waves/SIMD (LDS 151KB -> 1 block/CU). Latency-bound regime, so
// every GEMM phase is k-outer with 9-12 independent accumulator chains/wave:
//   QKV:  wave owns row-tile w4, all 9 (mat,et) weight tiles -> 9 chains,
//         1 ds_read + 9 weight loads per k-step.
//   FFN1: 12 chains (3 mt x 4 nt), 4 ds_reads + 3 w1T loads per k-step.
//   out-proj / FFN2: 12 chains (as in the 1893us version).
// FFN double-buffers U (sA <-> qkv scratch): 1 barrier/chunk, FFN1 global
// loads overlap FFN2 MFMAs.
__global__ __launch_bounds__(512, 2) void block_fused(
    const float* __restrict__ x,
    const float* __restrict__ bq, const float* __restrict__ bk, const float* __restrict__ bv,
    const float* __restrict__ bo, const float* __restrict__ b1, const float* __restrict__ b2,
    const float* __restrict__ g1, const float* __restrict__ be1,
    const float* __restrict__ g2, const float* __restrict__ be2,
    const unsigned short* __restrict__ wt,
    float* __restrict__ out) {
  // strides: 392 = 384+8 (row stride ≡ 4 mod 32 dwords -> 2-way bank alias only, 16B aligned)
  //          72  = 64+8  (same property)
  __shared__ __align__(16) unsigned short sH[64 * 392];   // h after LN1; h2 after LN2
  __shared__ __align__(16) unsigned short sA[64 * 392];   // attn concat; U buffer 0
  __shared__ __align__(16) unsigned short sS[25344];      // qkv sets | LN2 scratch | U buffer 1
  // sS carve (ushorts): sQ[set] at set*4608; sK[set] at 9216+set*4608; sVT[set] at 18432+set*3456

  const int tid  = threadIdx.x;
  const int wave = tid >> 6, lane = tid & 63;
  const int quad = lane >> 4, l15 = lane & 15;
  const int g = wave >> 2, w4 = wave & 3;    // head-set, wave-within-set
  const int b = blockIdx.x;

  const unsigned short* wqkvT = wt;
  const unsigned short* woT   = wt + 442368;
  const unsigned short* w1T   = wt + 589824;
  const unsigned short* w2T   = wt + 1179648;

  unsigned short* sQg = sS + g * 4608;
  unsigned short* sKg = sS + 9216 + g * 4608;
  unsigned short* sVg = sS + 18432 + g * 3456;

  // ================= Phase 0: LN1, x -> sH (bf16) =================
  {
    const int r = tid >> 3, sub = tid & 7;    // 8 threads per row
    const float* xr = x + ((size_t)b * 64 + r) * 384 + sub * 48;
    float s = 0.f, s2 = 0.f;
#pragma unroll
    for (int i = 0; i < 12; ++i) {
      float4 v = ((const float4*)xr)[i];
      s  += v.x + v.y + v.z + v.w;
      s2 += v.x * v.x + v.y * v.y + v.z * v.z + v.w * v.w;
    }
    s  += __shfl_xor(s, 1);  s  += __shfl_xor(s, 2);  s  += __shfl_xor(s, 4);
    s2 += __shfl_xor(s2, 1); s2 += __shfl_xor(s2, 2); s2 += __shfl_xor(s2, 4);
    float mu = s * (1.f / 384.f);
    float rstd = rsqrtf(s2 * (1.f / 384.f) - mu * mu + LNE);
#pragma unroll
    for (int i = 0; i < 12; ++i) {
      float4 v = ((const float4*)xr)[i];
      int c = sub * 48 + i * 4;
      float h0 = (v.x - mu) * rstd * g1[c + 0] + be1[c + 0];
      float h1 = (v.y - mu) * rstd * g1[c + 1] + be1[c + 1];
      float h2 = (v.z - mu) * rstd * g1[c + 2] + be1[c + 2];
      float h3 = (v.w - mu) * rstd * g1[c + 3] + be1[c + 3];
      *(uint2*)&sH[r * 392 + c] = make_uint2(pk2(h0, h1), pk2(h2, h3));
    }
  }
  __syncthreads();

  // ================= Phase 1: attention, 2 heads per iteration =================
#pragma unroll 1
  for (int hp = 0; hp < 4; ++hp) {
    const int h = hp * 2 + g;
    {   // zero-pad q/k cols 48..63 of own set (K=64 MFMA padding; P overwrote last iter)
      int set = tid >> 8, t2 = tid & 255;
      int rr = t2 >> 2, cc = 48 + (t2 & 3) * 4;
      *(uint2*)&sS[set * 4608 + rr * 72 + cc] = make_uint2(0, 0);            // q pad
      *(uint2*)&sS[9216 + set * 4608 + rr * 72 + cc] = make_uint2(0, 0);     // k pad
    }
    // --- QKV for this set's head: wave owns row-tile w4, 9 (mat,et) chains ---
    {
      f32x4 qacc[9];
#pragma unroll
      for (int j = 0; j < 9; ++j) qacc[j] = (f32x4){0.f, 0.f, 0.f, 0.f};
      const unsigned short* abase = sH + (w4 * 16 + l15) * 392 + quad * 8;
      const unsigned short* bbase = wqkvT + ((size_t)h * 48 + l15) * 384 + quad * 8;
#pragma unroll
      for (int k = 0; k < 12; ++k) {
        short8 a = *(const short8*)(abase + k * 32);
#pragma unroll
        for (int mat = 0; mat < 3; ++mat)
#pragma unroll
          for (int et = 0; et < 3; ++et) {
            short8 bb = *(const short8*)(bbase + (size_t)(mat * 384 + et * 16) * 384 + k * 32);
            qacc[mat * 3 + et] =
                __builtin_amdgcn_mfma_f32_16x16x32_bf16(a, bb, qacc[mat * 3 + et], 0, 0, 0);
          }
      }
#pragma unroll
      for (int mat = 0; mat < 3; ++mat) {
        const float* bias = (mat == 0) ? bq : ((mat == 1) ? bk : bv);
#pragma unroll
        for (int et = 0; et < 3; ++et) {
          f32x4 acc = qacc[mat * 3 + et];
          float bsv = bias[h * 48 + et * 16 + l15];
          if (mat == 2) {   // v -> sVT[e][s], contiguous in s -> b64 pack
            *(uint2*)&sVg[(et * 16 + l15) * 72 + w4 * 16 + quad * 4] =
                make_uint2(pk2(acc[0] + bsv, acc[1] + bsv), pk2(acc[2] + bsv, acc[3] + bsv));
          } else {          // q/k -> [t][e], scalar scatter (own rows)
            unsigned short* dst = (mat == 0) ? sQg : sKg;
#pragma unroll
            for (int i = 0; i < 4; ++i)
              dst[(w4 * 16 + quad * 4 + i) * 72 + et * 16 + l15] = f2bf(acc[i] + bsv);
          }
        }
      }
    }
    __syncthreads();

    // --- S = q k^T (wave owns rows 16*w4..+15), causal softmax in-register ---
    f32x4 sc[4];
#pragma unroll
    for (int ts = 0; ts < 4; ++ts) {
      f32x4 acc = {0.f, 0.f, 0.f, 0.f};
#pragma unroll
      for (int k = 0; k < 2; ++k) {
        short8 a  = *(const short8*)&sQg[(w4 * 16 + l15) * 72 + k * 32 + quad * 8];
        short8 bb = *(const short8*)&sKg[(ts * 16 + l15) * 72 + k * 32 + quad * 8];
        acc = __builtin_amdgcn_mfma_f32_16x16x32_bf16(a, bb, acc, 0, 0, 0);
      }
      sc[ts] = acc;
    }
    const float scale = 0.14433756729740645f;  // 48^-0.5
#pragma unroll
    for (int i = 0; i < 4; ++i) {
      int t = w4 * 16 + quad * 4 + i;
      float vv[4];
#pragma unroll
      for (int ts = 0; ts < 4; ++ts) {
        int s_ = ts * 16 + l15;
        float v = sc[ts][i] * scale;
        vv[ts] = (s_ <= t) ? v : -INFINITY;
      }
      float mx = fmaxf(fmaxf(vv[0], vv[1]), fmaxf(vv[2], vv[3]));
      mx = fmaxf(mx, __shfl_xor(mx, 1)); mx = fmaxf(mx, __shfl_xor(mx, 2));
      mx = fmaxf(mx, __shfl_xor(mx, 4)); mx = fmaxf(mx, __shfl_xor(mx, 8));
      float sum = 0.f;
#pragma unroll
      for (int ts = 0; ts < 4; ++ts) { vv[ts] = __expf(vv[ts] - mx); sum += vv[ts]; }
      sum += __shfl_xor(sum, 1); sum += __shfl_xor(sum, 2);
      sum += __shfl_xor(sum, 4); sum += __shfl_xor(sum, 8);
      float inv = 1.f / sum;
#pragma unroll
      for (int ts = 0; ts < 4; ++ts)           // P -> sQ[t][s] (q is dead; own rows only)
        sQg[t * 72 + ts * 16 + l15] = f2bf(vv[ts] * inv);
    }
    // --- attn^T = V^T P^T ; write attn[t][h*48+e] (b64 pack) ---
#pragma unroll
    for (int et = 0; et < 3; ++et) {
      f32x4 acc = {0.f, 0.f, 0.f, 0.f};
#pragma unroll
      for (int k = 0; k < 2; ++k) {
        short8 a  = *(const short8*)&sVg[(et * 16 + l15) * 72 + k * 32 + quad * 8];
        short8 bb = *(const short8*)&sQg[(w4 * 16 + l15) * 72 + k * 32 + quad * 8];
        acc = __builtin_amdgcn_mfma_f32_16x16x32_bf16(a, bb, acc, 0, 0, 0);
      }
      *(uint2*)&sA[(w4 * 16 + l15) * 392 + h * 48 + et * 16 + quad * 4] =
          make_uint2(pk2(acc[0], acc[1]), pk2(acc[2], acc[3]));
    }
    __syncthreads();
  }

  // ================= Phase 2: out-proj + residual + LN2 =================
  {
    const int mt2 = wave >> 1, nh = wave & 1;  // row-tile, n-half
    float* sRed = (float*)sS;                  // qkv scratch dead -> LN2 cross-wave scratch
    f32x4 oacc[12];
#pragma unroll
    for (int nl = 0; nl < 12; ++nl) oacc[nl] = (f32x4){0.f, 0.f, 0.f, 0.f};
#pragma unroll 2
    for (int k = 0; k < 12; ++k) {
      short8 a = *(const short8*)&sA[(mt2 * 16 + l15) * 392 + k * 32 + quad * 8];
#pragma unroll
      for (int nl = 0; nl < 12; ++nl) {
        int nt = nh * 12 + nl;
        short8 bb = *(const short8*)(woT + (size_t)(nt * 16 + l15) * 384 + k * 32 + quad * 8);
        oacc[nl] = __builtin_amdgcn_mfma_f32_16x16x32_bf16(a, bb, oacc[nl], 0, 0, 0);
      }
    }
#pragma unroll
    for (int nl = 0; nl < 12; ++nl) {
      int nt = nh * 12 + nl;
      float bov = bo[nt * 16 + l15];
#pragma unroll
      for (int i = 0; i < 4; ++i) {
        float hv = bf2f(sH[(mt2 * 16 + quad * 4 + i) * 392 + nt * 16 + l15]);
        oacc[nl][i] += bov + hv;    // r = h + attn@wo + bo
      }
    }
    // per-wave partial row stats (192 of 384 cols) -> LDS -> combine with partner
    float sown[4], s2own[4];
#pragma unroll
    for (int i = 0; i < 4; ++i) {
      float s = 0.f, s2 = 0.f;
#pragma unroll
      for (int nl = 0; nl < 12; ++nl) { float v = oacc[nl][i]; s += v; s2 += v * v; }
      s  += __shfl_xor(s, 1);  s  += __shfl_xor(s, 2);  s  += __shfl_xor(s, 4);  s  += __shfl_xor(s, 8);
      s2 += __shfl_xor(s2, 1); s2 += __shfl_xor(s2, 2); s2 += __shfl_xor(s2, 4); s2 += __shfl_xor(s2, 8);
      sown[i] = s; s2own[i] = s2;
      if (l15 == 0) {
        int row = mt2 * 16 + quad * 4 + i;
        sRed[(nh * 64 + row) * 2 + 0] = s;
        sRed[(nh * 64 + row) * 2 + 1] = s2;
      }
    }
    __syncthreads();
    float mu_[4], rstd_[4];
#pragma unroll
    for (int i = 0; i < 4; ++i) {
      int row = mt2 * 16 + quad * 4 + i;
      float st  = sown[i]  + sRed[((nh ^ 1) * 64 + row) * 2 + 0];
      float s2t = s2own[i] + sRed[((nh ^ 1) * 64 + row) * 2 + 1];
      float mu = st * (1.f / 384.f);
      mu_[i] = mu;
      rstd_[i] = rsqrtf(s2t * (1.f / 384.f) - mu * mu + LNE);
    }
#pragma unroll
    for (int nl = 0; nl < 12; ++nl) {
      int n = (nh * 12 + nl) * 16 + l15;
      float gv = g2[n], bev = be2[n];
#pragma unroll
      for (int i = 0; i < 4; ++i) {
        float h2v = (oacc[nl][i] - mu_[i]) * rstd_[i] * gv + bev;
        sH[(mt2 * 16 + quad * 4 + i) * 392 + n] = f2bf(h2v);   // h2 overwrites h (own region)
      }
    }
  }
  __syncthreads();

  // ================= Phase 3: FFN, double-buffered chunks of 384 over 1536 =================
  f32x4 facc[4][3];
#pragma unroll
  for (int mt = 0; mt < 4; ++mt)
#pragma unroll
    for (int nl = 0; nl < 3; ++nl) facc[mt][nl] = (f32x4){0.f, 0.f, 0.f, 0.f};

  // FFN1: U^T = w1_chunk^T @ h2^T ; wave owns 3 m-tiles x 4 n-tiles = 12 chains
  auto FFN1 = [&](int c, unsigned short* U) {
    f32x4 acc[3][4];
#pragma unroll
    for (int ml = 0; ml < 3; ++ml)
#pragma unroll
      for (int nt = 0; nt < 4; ++nt) acc[ml][nt] = (f32x4){0.f, 0.f, 0.f, 0.f};
    const unsigned short* apb = w1T + (size_t)(c * 384 + wave * 48 + l15) * 384 + quad * 8;
#pragma unroll
    for (int k = 0; k < 12; ++k) {
      short8 bb[4];
#pragma unroll
      for (int nt = 0; nt < 4; ++nt)
        bb[nt] = *(const short8*)&sH[(nt * 16 + l15) * 392 + k * 32 + quad * 8];
#pragma unroll
      for (int ml = 0; ml < 3; ++ml) {
        short8 a = *(const short8*)(apb + (size_t)(ml * 16) * 384 + k * 32);
#pragma unroll
        for (int nt = 0; nt < 4; ++nt)
          acc[ml][nt] = __builtin_amdgcn_mfma_f32_16x16x32_bf16(a, bb[nt], acc[ml][nt], 0, 0, 0);
      }
    }
#pragma unroll
    for (int ml = 0; ml < 3; ++ml) {
      int mt = wave * 3 + ml;
      int rbase = c * 384 + mt * 16 + quad * 4;
#pragma unroll
      for (int nt = 0; nt < 4; ++nt) {
        float u0 = fmaxf(acc[ml][nt][0] + b1[rbase + 0], 0.f);
        float u1 = fmaxf(acc[ml][nt][1] + b1[rbase + 1], 0.f);
        float u2 = fmaxf(acc[ml][nt][2] + b1[rbase + 2], 0.f);
        float u3 = fmaxf(acc[ml][nt][3] + b1[rbase + 3], 0.f);
        *(uint2*)&U[(nt * 16 + l15) * 392 + mt * 16 + quad * 4] =
            make_uint2(pk2(u0, u1), pk2(u2, u3));
      }
    }
  };
  // FFN2: wave owns n-tiles wave*3..+2, all 4 row-tiles = 12 chains
  auto FFN2 = [&](int c, const unsigned short* U) {
#pragma unroll 2
    for (int k = 0; k < 12; ++k) {
      short8 a[4];
#pragma unroll
      for (int mt = 0; mt < 4; ++mt)
        a[mt] = *(const short8*)&U[(mt * 16 + l15) * 392 + k * 32 + quad * 8];
#pragma unroll
      for (int nl = 0; nl < 3; ++nl) {
        int n = (wave * 3 + nl) * 16 + l15;
        short8 bb = *(const short8*)(w2T + (size_t)n * 1536 + c * 384 + k * 32 + quad * 8);
#pragma unroll
        for (int mt = 0; mt < 4; ++mt)
          facc[mt][nl] = __builtin_amdgcn_mfma_f32_16x16x32_bf16(a[mt], bb, facc[mt][nl], 0, 0, 0);
      }
    }
  };

  FFN1(0, sA);
  __syncthreads();
#pragma unroll 1
  for (int c = 0; c < 4; ++c) {
    if (c < 3) FFN1(c + 1, (c & 1) ? sA : sS);  // write next chunk to the other buffer
    FFN2(c, (c & 1) ? sS : sA);                 // read current chunk
    __syncthreads();
  }

  // ================= Epilogue: out = h2 + ff + b2 =================
#pragma unroll
  for (int nl = 0; nl < 3; ++nl) {
    int n = (wave * 3 + nl) * 16 + l15;
    float b2v = b2[n];
#pragma unroll
    for (int mt = 0; mt < 4; ++mt) {
#pragma unroll
      for (int i = 0; i < 4; ++i) {
        int t = mt * 16 + quad * 4 + i;
        float v = facc[mt][nl][i] + b2v + bf2f(sH[t * 392 + n]);
        out[((size_t)b * 64 + t) * 384 + n] = v;
      }
    }
  }
}

extern "C" void kernel_launch(void* const* d_in, const int* in_sizes, int n_in,
                              void* d_out, int out_size, void* d_ws, size_t ws_size,
                              hipStream_t stream) {
  const float* x   = (const float*)d_in[0];
  const float* wq  = (const float*)d_in[1];
  const float* bq  = (const float*)d_in[2];
  const float* wk  = (const float*)d_in[3];
  const float* bk  = (const float*)d_in[4];
  const float* wv  = (const float*)d_in[5];
  const float* bv  = (const float*)d_in[6];
  const float* wo  = (const float*)d_in[7];
  const float* bo  = (const float*)d_in[8];
  const float* w1  = (const float*)d_in[9];
  const float* b1  = (const float*)d_in[10];
  const float* w2  = (const float*)d_in[11];
  const float* b2  = (const float*)d_in[12];
  const float* g1  = (const float*)d_in[13];
  const float* be1 = (const float*)d_in[14];
  const float* g2  = (const float*)d_in[15];
  const float* be2 = (const float*)d_in[16];
  unsigned short* wt = (unsigned short*)d_ws;
  float* out = (float*)d_out;

  int nbatch = in_sizes[0] / (64 * 384);    // 2048
  prep_kernel<<<(1769472 + 255) / 256, 256, 0, stream>>>(wq, wk, wv, wo, w1, w2, wt);
  block_fused<<<nbatch, 512, 0, stream>>>(x, bq, bk, bv, bo, b1, b2,
                                          g1, be1, g2, be2, wt, out);
}

// Round 4
// 1340.743 us; speedup vs baseline: 2.5947x; 1.5582x over previous
//
#include <hip/hip_runtime.h>

typedef __attribute__((ext_vector_type(8))) short short8;
typedef __attribute__((ext_vector_type(4))) float f32x4;

#define LNE 1e-5f

__device__ __forceinline__ unsigned short f2bf(float f) {
  union { float f; unsigned int u; } v; v.f = f;
  unsigned int r = v.u + 0x7fffu + ((v.u >> 16) & 1u);
  return (unsigned short)(r >> 16);
}
__device__ __forceinline__ float bf2f(unsigned short s) {
  union { unsigned int u; float f; } v; v.u = ((unsigned int)s) << 16;
  return v.f;
}
__device__ __forceinline__ unsigned int pk2(float a, float b) {
  return (unsigned int)f2bf(a) | ((unsigned int)f2bf(b) << 16);
}
__device__ __forceinline__ short8 ld8(const unsigned short* p, int k) {
  return *(const short8*)(p + k * 32);
}

// ---- weight prep: fp32 -> bf16, transposed to [n][k] ----
// ws layout (ushort elems):
//   wqkvT [1152][384]  rows: mat*384 + head*48 + e       (0 .. 442368)
//   woT   [384][384]   woT[n][d] = wo[d][n]              (442368 .. 589824)
//   w1T   [1536][384]  w1T[n][d] = w1[d][n]              (589824 .. 1179648)
//   w2T   [384][1536]  w2T[n][c] = w2[c][n]              (1179648 .. 1769472)
__global__ void prep_kernel(const float* __restrict__ wq, const float* __restrict__ wk,
                            const float* __restrict__ wv, const float* __restrict__ wo,
                            const float* __restrict__ w1, const float* __restrict__ w2,
                            unsigned short* __restrict__ ws) {
  int idx = blockIdx.x * 256 + threadIdx.x;
  if (idx < 442368) {
    int n = idx / 384, d = idx % 384;
    int mat = n / 384, rem = n % 384, head = rem / 48, e = rem % 48;
    const float* w = (mat == 0) ? wq : ((mat == 1) ? wk : wv);
    ws[idx] = f2bf(w[(head * 384 + d) * 48 + e]);
  } else if (idx < 589824) {
    int j = idx - 442368; int n = j / 384, d = j % 384;
    ws[idx] = f2bf(wo[d * 384 + n]);
  } else if (idx < 1179648) {
    int j = idx - 589824; int n = j / 384, d = j % 384;
    ws[idx] = f2bf(w1[d * 1536 + n]);
  } else if (idx < 1769472) {
    int j = idx - 1179648; int n = j / 1536, c = j % 1536;
    ws[idx] = f2bf(w2[c * 384 + n]);
  }
}

// ---- fused transformer block: one workgroup (512 thr / 8 waves) per batch ----
// Latency-bound at 2 waves/SIMD (LDS 151KB -> 1 block/CU). R4: every global-B
// GEMM phase uses (a) 4:1 MFMA:load ratio (each weight frag feeds all 4 row
// tiles) and (b) explicit 3-deep register prefetch (4-slot rotating buffer,
// load k+3 while computing k) -> ~9 outstanding 16B L2 loads per wave instead
// of ~3, covering ~200cyc L2 latency with ~300cyc of compute.
__global__ __launch_bounds__(512, 2) void block_fused(
    const float* __restrict__ x,
    const float* __restrict__ bq, const float* __restrict__ bk, const float* __restrict__ bv,
    const float* __restrict__ bo, const float* __restrict__ b1, const float* __restrict__ b2,
    const float* __restrict__ g1, const float* __restrict__ be1,
    const float* __restrict__ g2, const float* __restrict__ be2,
    const unsigned short* __restrict__ wt,
    float* __restrict__ out) {
  // strides: 392 = 384+8 (row stride ≡ 4 mod 32 dwords -> 2-way bank alias only, 16B aligned)
  //          72  = 64+8  (same property)
  __shared__ __align__(16) unsigned short sH[64 * 392];   // h after LN1; h2 after LN2
  __shared__ __align__(16) unsigned short sA[64 * 392];   // attn concat; U buffer 0
  __shared__ __align__(16) unsigned short sS[25344];      // qkv sets | LN2 scratch | U buffer 1
  // sS carve (ushorts): sQ[set] at set*4608; sK[set] at 9216+set*4608; sVT[set] at 18432+set*3456

  const int tid  = threadIdx.x;
  const int wave = tid >> 6, lane = tid & 63;
  const int quad = lane >> 4, l15 = lane & 15;
  const int g = wave >> 2, w4 = wave & 3;    // head-set, wave-within-set
  const int b = blockIdx.x;

  const unsigned short* wqkvT = wt;
  const unsigned short* woT   = wt + 442368;
  const unsigned short* w1T   = wt + 589824;
  const unsigned short* w2T   = wt + 1179648;

  unsigned short* sQg = sS + g * 4608;
  unsigned short* sKg = sS + 9216 + g * 4608;
  unsigned short* sVg = sS + 18432 + g * 3456;

  // ================= Phase 0: LN1, x -> sH (bf16); zero q/k pads =================
  {
    {   // zero-pad q/k cols 48..63 of both sets (K=64 MFMA padding)
      int set = tid >> 8, j = tid & 255;
      int r = j >> 2, cc = 48 + (j & 3) * 4;
      *(uint2*)&sS[set * 4608 + r * 72 + cc] = make_uint2(0, 0);          // q pad
      *(uint2*)&sS[9216 + set * 4608 + r * 72 + cc] = make_uint2(0, 0);   // k pad
    }
    const int r = tid >> 3, sub = tid & 7;    // 8 threads per row
    const float* xr = x + ((size_t)b * 64 + r) * 384 + sub * 48;
    float s = 0.f, s2 = 0.f;
#pragma unroll
    for (int i = 0; i < 12; ++i) {
      float4 v = ((const float4*)xr)[i];
      s  += v.x + v.y + v.z + v.w;
      s2 += v.x * v.x + v.y * v.y + v.z * v.z + v.w * v.w;
    }
    s  += __shfl_xor(s, 1);  s  += __shfl_xor(s, 2);  s  += __shfl_xor(s, 4);
    s2 += __shfl_xor(s2, 1); s2 += __shfl_xor(s2, 2); s2 += __shfl_xor(s2, 4);
    float mu = s * (1.f / 384.f);
    float rstd = rsqrtf(s2 * (1.f / 384.f) - mu * mu + LNE);
#pragma unroll
    for (int i = 0; i < 12; ++i) {
      float4 v = ((const float4*)xr)[i];
      int c = sub * 48 + i * 4;
      float h0 = (v.x - mu) * rstd * g1[c + 0] + be1[c + 0];
      float h1 = (v.y - mu) * rstd * g1[c + 1] + be1[c + 1];
      float h2 = (v.z - mu) * rstd * g1[c + 2] + be1[c + 2];
      float h3 = (v.w - mu) * rstd * g1[c + 3] + be1[c + 3];
      *(uint2*)&sH[r * 392 + c] = make_uint2(pk2(h0, h1), pk2(h2, h3));
    }
  }
  __syncthreads();

  // ================= Phase 1: attention, 2 heads per iteration =================
#pragma unroll 1
  for (int hp = 0; hp < 4; ++hp) {
    const int h = hp * 2 + g;
    if (hp) {   // re-zero q pad (P overwrote all 64 cols last iter)
      int set = tid >> 8, j = tid & 255;
      int r = j >> 2, cc = 48 + (j & 3) * 4;
      *(uint2*)&sS[set * 4608 + r * 72 + cc] = make_uint2(0, 0);
    }
    // --- QKV for this set's head: wave owns streams {w4, w4+4} (+8 if w4==g),
    //     each weight stream feeds all 4 row-tiles; 3-deep prefetch ---
    {
      const int s0m = w4 / 3, s0e = w4 % 3;            // stream w4
      const int s1m = (w4 + 4) / 3, s1e = (w4 + 4) % 3; // stream w4+4
      const bool has2 = (w4 == g);                      // stream 8 = (mat2, et2)
      const unsigned short* bp0 = wqkvT + ((size_t)(s0m * 8 + h) * 48 + s0e * 16 + l15) * 384 + quad * 8;
      const unsigned short* bp1 = wqkvT + ((size_t)(s1m * 8 + h) * 48 + s1e * 16 + l15) * 384 + quad * 8;
      const unsigned short* bp2 = wqkvT + ((size_t)(16 + h) * 48 + 32 + l15) * 384 + quad * 8;
      const unsigned short* abase = sH + l15 * 392 + quad * 8;

      f32x4 acc0[4], acc1[4], acc2[4];
#pragma unroll
      for (int mt = 0; mt < 4; ++mt) {
        acc0[mt] = (f32x4){0.f, 0.f, 0.f, 0.f};
        acc1[mt] = (f32x4){0.f, 0.f, 0.f, 0.f};
        acc2[mt] = (f32x4){0.f, 0.f, 0.f, 0.f};
      }
      short8 b0[4], b1[4], b2[4];
#pragma unroll
      for (int k = 0; k < 3; ++k) {
        b0[k] = ld8(bp0, k); b1[k] = ld8(bp1, k);
        if (has2) b2[k] = ld8(bp2, k);
      }
#pragma unroll
      for (int k = 0; k < 12; ++k) {
        if (k < 9) {
          int sl = (k + 3) & 3;
          b0[sl] = ld8(bp0, k + 3); b1[sl] = ld8(bp1, k + 3);
          if (has2) b2[sl] = ld8(bp2, k + 3);
        }
        short8 a[4];
#pragma unroll
        for (int mt = 0; mt < 4; ++mt) a[mt] = *(const short8*)(abase + mt * 16 * 392 + k * 32);
        int sl = k & 3;
#pragma unroll
        for (int mt = 0; mt < 4; ++mt)
          acc0[mt] = __builtin_amdgcn_mfma_f32_16x16x32_bf16(a[mt], b0[sl], acc0[mt], 0, 0, 0);
#pragma unroll
        for (int mt = 0; mt < 4; ++mt)
          acc1[mt] = __builtin_amdgcn_mfma_f32_16x16x32_bf16(a[mt], b1[sl], acc1[mt], 0, 0, 0);
        if (has2) {
#pragma unroll
          for (int mt = 0; mt < 4; ++mt)
            acc2[mt] = __builtin_amdgcn_mfma_f32_16x16x32_bf16(a[mt], b2[sl], acc2[mt], 0, 0, 0);
        }
      }
      auto wrQKV = [&](int mat, int et, f32x4* acc) {
        const float* bias = (mat == 0) ? bq : ((mat == 1) ? bk : bv);
        float bsv = bias[h * 48 + et * 16 + l15];
        if (mat == 2) {   // v -> sVT[e][s], contiguous in s -> b64 pack
#pragma unroll
          for (int mt = 0; mt < 4; ++mt)
            *(uint2*)&sVg[(et * 16 + l15) * 72 + mt * 16 + quad * 4] =
                make_uint2(pk2(acc[mt][0] + bsv, acc[mt][1] + bsv),
                           pk2(acc[mt][2] + bsv, acc[mt][3] + bsv));
        } else {          // q/k -> [t][e], scalar scatter
          unsigned short* dst = (mat == 0) ? sQg : sKg;
#pragma unroll
          for (int mt = 0; mt < 4; ++mt)
#pragma unroll
            for (int i = 0; i < 4; ++i)
              dst[(mt * 16 + quad * 4 + i) * 72 + et * 16 + l15] = f2bf(acc[mt][i] + bsv);
        }
      };
      wrQKV(s0m, s0e, acc0);
      wrQKV(s1m, s1e, acc1);
      if (has2) wrQKV(2, 2, acc2);
    }
    __syncthreads();

    // --- S = q k^T (wave owns rows 16*w4..+15), causal softmax in-register ---
    f32x4 sc[4];
#pragma unroll
    for (int ts = 0; ts < 4; ++ts) {
      f32x4 acc = {0.f, 0.f, 0.f, 0.f};
#pragma unroll
      for (int k = 0; k < 2; ++k) {
        short8 a  = *(const short8*)&sQg[(w4 * 16 + l15) * 72 + k * 32 + quad * 8];
        short8 bb = *(const short8*)&sKg[(ts * 16 + l15) * 72 + k * 32 + quad * 8];
        acc = __builtin_amdgcn_mfma_f32_16x16x32_bf16(a, bb, acc, 0, 0, 0);
      }
      sc[ts] = acc;
    }
    const float scale = 0.14433756729740645f;  // 48^-0.5
#pragma unroll
    for (int i = 0; i < 4; ++i) {
      int t = w4 * 16 + quad * 4 + i;
      float vv[4];
#pragma unroll
      for (int ts = 0; ts < 4; ++ts) {
        int s_ = ts * 16 + l15;
        float v = sc[ts][i] * scale;
        vv[ts] = (s_ <= t) ? v : -INFINITY;
      }
      float mx = fmaxf(fmaxf(vv[0], vv[1]), fmaxf(vv[2], vv[3]));
      mx = fmaxf(mx, __shfl_xor(mx, 1)); mx = fmaxf(mx, __shfl_xor(mx, 2));
      mx = fmaxf(mx, __shfl_xor(mx, 4)); mx = fmaxf(mx, __shfl_xor(mx, 8));
      float sum = 0.f;
#pragma unroll
      for (int ts = 0; ts < 4; ++ts) { vv[ts] = __expf(vv[ts] - mx); sum += vv[ts]; }
      sum += __shfl_xor(sum, 1); sum += __shfl_xor(sum, 2);
      sum += __shfl_xor(sum, 4); sum += __shfl_xor(sum, 8);
      float inv = 1.f / sum;
#pragma unroll
      for (int ts = 0; ts < 4; ++ts)           // P -> sQ[t][s] (q is dead; own rows only)
        sQg[t * 72 + ts * 16 + l15] = f2bf(vv[ts] * inv);
    }
    // --- attn^T = V^T P^T ; write attn[t][h*48+e] (b64 pack) ---
#pragma unroll
    for (int et = 0; et < 3; ++et) {
      f32x4 acc = {0.f, 0.f, 0.f, 0.f};
#pragma unroll
      for (int k = 0; k < 2; ++k) {
        short8 a  = *(const short8*)&sVg[(et * 16 + l15) * 72 + k * 32 + quad * 8];
        short8 bb = *(const short8*)&sQg[(w4 * 16 + l15) * 72 + k * 32 + quad * 8];
        acc = __builtin_amdgcn_mfma_f32_16x16x32_bf16(a, bb, acc, 0, 0, 0);
      }
      *(uint2*)&sA[(w4 * 16 + l15) * 392 + h * 48 + et * 16 + quad * 4] =
          make_uint2(pk2(acc[0], acc[1]), pk2(acc[2], acc[3]));
    }
    __syncthreads();
  }

  // ================= Phase 2: out-proj + residual + LN2 =================
  // wave owns 3 n-streams (nt = wave*3..+2) x all 4 row-tiles; 3-deep prefetch.
  {
    float* sRedS  = (float*)sS;        // 64 rows x 8 waves partial sums
    float* sRedS2 = (float*)sS + 512;
    const unsigned short* bp[3];
#pragma unroll
    for (int nl = 0; nl < 3; ++nl)
      bp[nl] = woT + (size_t)((wave * 3 + nl) * 16 + l15) * 384 + quad * 8;
    f32x4 oacc[3][4];
#pragma unroll
    for (int nl = 0; nl < 3; ++nl)
#pragma unroll
      for (int mt = 0; mt < 4; ++mt) oacc[nl][mt] = (f32x4){0.f, 0.f, 0.f, 0.f};
    short8 bb[3][4];
#pragma unroll
    for (int k = 0; k < 3; ++k)
#pragma unroll
      for (int nl = 0; nl < 3; ++nl) bb[nl][k] = ld8(bp[nl], k);
#pragma unroll
    for (int k = 0; k < 12; ++k) {
      if (k < 9) {
        int sl = (k + 3) & 3;
#pragma unroll
        for (int nl = 0; nl < 3; ++nl) bb[nl][sl] = ld8(bp[nl], k + 3);
      }
      short8 a[4];
#pragma unroll
      for (int mt = 0; mt < 4; ++mt)
        a[mt] = *(const short8*)&sA[(mt * 16 + l15) * 392 + k * 32 + quad * 8];
      int sl = k & 3;
#pragma unroll
      for (int nl = 0; nl < 3; ++nl)
#pragma unroll
        for (int mt = 0; mt < 4; ++mt)
          oacc[nl][mt] = __builtin_amdgcn_mfma_f32_16x16x32_bf16(a[mt], bb[nl][sl], oacc[nl][mt], 0, 0, 0);
    }
    // bias + residual
#pragma unroll
    for (int nl = 0; nl < 3; ++nl) {
      int n = (wave * 3 + nl) * 16 + l15;
      float bov = bo[n];
#pragma unroll
      for (int mt = 0; mt < 4; ++mt)
#pragma unroll
        for (int i = 0; i < 4; ++i)
          oacc[nl][mt][i] += bov + bf2f(sH[(mt * 16 + quad * 4 + i) * 392 + n]);
    }
    // per-wave partial row stats (48 cols) -> LDS -> combine 8 waves
#pragma unroll
    for (int mt = 0; mt < 4; ++mt)
#pragma unroll
      for (int i = 0; i < 4; ++i) {
        float s = oacc[0][mt][i] + oacc[1][mt][i] + oacc[2][mt][i];
        float s2 = oacc[0][mt][i] * oacc[0][mt][i] + oacc[1][mt][i] * oacc[1][mt][i]
                 + oacc[2][mt][i] * oacc[2][mt][i];
        s  += __shfl_xor(s, 1);  s  += __shfl_xor(s, 2);  s  += __shfl_xor(s, 4);  s  += __shfl_xor(s, 8);
        s2 += __shfl_xor(s2, 1); s2 += __shfl_xor(s2, 2); s2 += __shfl_xor(s2, 4); s2 += __shfl_xor(s2, 8);
        if (l15 == 0) {
          int row = mt * 16 + quad * 4 + i;
          sRedS[row * 8 + wave] = s;
          sRedS2[row * 8 + wave] = s2;
        }
      }
    __syncthreads();
    float mu_[4][4], rs_[4][4];
#pragma unroll
    for (int mt = 0; mt < 4; ++mt)
#pragma unroll
      for (int i = 0; i < 4; ++i) {
        int row = mt * 16 + quad * 4 + i;
        float4 p0 = *(float4*)&sRedS[row * 8], p1 = *(float4*)&sRedS[row * 8 + 4];
        float4 q0 = *(float4*)&sRedS2[row * 8], q1 = *(float4*)&sRedS2[row * 8 + 4];
        float st  = p0.x + p0.y + p0.z + p0.w + p1.x + p1.y + p1.z + p1.w;
        float s2t = q0.x + q0.y + q0.z + q0.w + q1.x + q1.y + q1.z + q1.w;
        float mu = st * (1.f / 384.f);
        mu_[mt][i] = mu;
        rs_[mt][i] = rsqrtf(s2t * (1.f / 384.f) - mu * mu + LNE);
      }
#pragma unroll
    for (int nl = 0; nl < 3; ++nl) {
      int n = (wave * 3 + nl) * 16 + l15;
      float gv = g2[n], bev = be2[n];
#pragma unroll
      for (int mt = 0; mt < 4; ++mt)
#pragma unroll
        for (int i = 0; i < 4; ++i) {
          float h2v = (oacc[nl][mt][i] - mu_[mt][i]) * rs_[mt][i] * gv + bev;
          sH[(mt * 16 + quad * 4 + i) * 392 + n] = f2bf(h2v);   // h2 (own rowsxcols region)
        }
    }
  }
  __syncthreads();

  // ================= Phase 3: FFN, double-buffered chunks of 384 over 1536 =================
  f32x4 facc[4][3];
#pragma unroll
  for (int mt = 0; mt < 4; ++mt)
#pragma unroll
    for (int nl = 0; nl < 3; ++nl) facc[mt][nl] = (f32x4){0.f, 0.f, 0.f, 0.f};

  // FFN1: U^T = w1_chunk^T @ h2^T ; 3 A-streams (w1T rows) x 4 nt; 3-deep prefetch
  auto FFN1 = [&](int c, unsigned short* U) {
    const unsigned short* ap[3];
#pragma unroll
    for (int ml = 0; ml < 3; ++ml)
      ap[ml] = w1T + (size_t)(c * 384 + (wave * 3 + ml) * 16 + l15) * 384 + quad * 8;
    f32x4 acc[3][4];
#pragma unroll
    for (int ml = 0; ml < 3; ++ml)
#pragma unroll
      for (int nt = 0; nt < 4; ++nt) acc[ml][nt] = (f32x4){0.f, 0.f, 0.f, 0.f};
    short8 av[3][4];
#pragma unroll
    for (int k = 0; k < 3; ++k)
#pragma unroll
      for (int ml = 0; ml < 3; ++ml) av[ml][k] = ld8(ap[ml], k);
#pragma unroll
    for (int k = 0; k < 12; ++k) {
      if (k < 9) {
        int sl = (k + 3) & 3;
#pragma unroll
        for (int ml = 0; ml < 3; ++ml) av[ml][sl] = ld8(ap[ml], k + 3);
      }
      short8 bb[4];
#pragma unroll
      for (int nt = 0; nt < 4; ++nt)
        bb[nt] = *(const short8*)&sH[(nt * 16 + l15) * 392 + k * 32 + quad * 8];
      int sl = k & 3;
#pragma unroll
      for (int ml = 0; ml < 3; ++ml)
#pragma unroll
        for (int nt = 0; nt < 4; ++nt)
          acc[ml][nt] = __builtin_amdgcn_mfma_f32_16x16x32_bf16(av[ml][sl], bb[nt], acc[ml][nt], 0, 0, 0);
    }
#pragma unroll
    for (int ml = 0; ml < 3; ++ml) {
      int mt = wave * 3 + ml;
      int rbase = c * 384 + mt * 16 + quad * 4;
#pragma unroll
      for (int nt = 0; nt < 4; ++nt) {
        float u0 = fmaxf(acc[ml][nt][0] + b1[rbase + 0], 0.f);
        float u1 = fmaxf(acc[ml][nt][1] + b1[rbase + 1], 0.f);
        float u2 = fmaxf(acc[ml][nt][2] + b1[rbase + 2], 0.f);
        float u3 = fmaxf(acc[ml][nt][3] + b1[rbase + 3], 0.f);
        *(uint2*)&U[(nt * 16 + l15) * 392 + mt * 16 + quad * 4] =
            make_uint2(pk2(u0, u1), pk2(u2, u3));
      }
    }
  };
  // FFN2: 3 B-streams (w2T rows) x 4 mt; 3-deep prefetch
  auto FFN2 = [&](int c, const unsigned short* U) {
    const unsigned short* bp[3];
#pragma unroll
    for (int nl = 0; nl < 3; ++nl)
      bp[nl] = w2T + (size_t)((wave * 3 + nl) * 16 + l15) * 1536 + c * 384 + quad * 8;
    short8 bb[3][4];
#pragma unroll
    for (int k = 0; k < 3; ++k)
#pragma unroll
      for (int nl = 0; nl < 3; ++nl) bb[nl][k] = ld8(bp[nl], k);
#pragma unroll
    for (int k = 0; k < 12; ++k) {
      if (k < 9) {
        int sl = (k + 3) & 3;
#pragma unroll
        for (int nl = 0; nl < 3; ++nl) bb[nl][sl] = ld8(bp[nl], k + 3);
      }
      short8 a[4];
#pragma unroll
      for (int mt = 0; mt < 4; ++mt)
        a[mt] = *(const short8*)&U[(mt * 16 + l15) * 392 + k * 32 + quad * 8];
      int sl = k & 3;
#pragma unroll
      for (int nl = 0; nl < 3; ++nl)
#pragma unroll
        for (int mt = 0; mt < 4; ++mt)
          facc[mt][nl] = __builtin_amdgcn_mfma_f32_16x16x32_bf16(a[mt], bb[nl][sl], facc[mt][nl], 0, 0, 0);
    }
  };

  FFN1(0, sA);
  __syncthreads();
#pragma unroll 1
  for (int c = 0; c < 4; ++c) {
    if (c < 3) FFN1(c + 1, (c & 1) ? sA : sS);  // write next chunk to the other buffer
    FFN2(c, (c & 1) ? sS : sA);                 // read current chunk
    __syncthreads();
  }

  // ================= Epilogue: out = h2 + ff + b2 =================
#pragma unroll
  for (int nl = 0; nl < 3; ++nl) {
    int n = (wave * 3 + nl) * 16 + l15;
    float b2v = b2[n];
#pragma unroll
    for (int mt = 0; mt < 4; ++mt) {
#pragma unroll
      for (int i = 0; i < 4; ++i) {
        int t = mt * 16 + quad * 4 + i;
        float v = facc[mt][nl][i] + b2v + bf2f(sH[t * 392 + n]);
        out[((size_t)b * 64 + t) * 384 + n] = v;
      }
    }
  }
}

extern "C" void kernel_launch(void* const* d_in, const int* in_sizes, int n_in,
                              void* d_out, int out_size, void* d_ws, size_t ws_size,
                              hipStream_t stream) {
  const float* x   = (const float*)d_in[0];
  const float* wq  = (const float*)d_in[1];
  const float* bq  = (const float*)d_in[2];
  const float* wk  = (const float*)d_in[3];
  const float* bk  = (const float*)d_in[4];
  const float* wv  = (const float*)d_in[5];
  const float* bv  = (const float*)d_in[6];
  const float* wo  = (const float*)d_in[7];
  const float* bo  = (const float*)d_in[8];
  const float* w1  = (const float*)d_in[9];
  const float* b1  = (const float*)d_in[10];
  const float* w2  = (const float*)d_in[11];
  const float* b2  = (const float*)d_in[12];
  const float* g1  = (const float*)d_in[13];
  const float* be1 = (const float*)d_in[14];
  const float* g2  = (const float*)d_in[15];
  const float* be2 = (const float*)d_in[16];
  unsigned short* wt = (unsigned short*)d_ws;
  float* out = (float*)d_out;

  int nbatch = in_sizes[0] / (64 * 384);    // 2048
  prep_kernel<<<(1769472 + 255) / 256, 256, 0, stream>>>(wq, wk, wv, wo, w1, w2, wt);
  block_fused<<<nbatch, 512, 0, stream>>>(x, bq, bk, bv, bo, b1, b2,
                                          g1, be1, g2, be2, wt, out);
}